// Round 9
// baseline (943.387 us; speedup 1.0000x reference)
//
#include <hip/hip_runtime.h>
#include <math.h>

#define D 256
#define MARGIN 0.075f

typedef __bf16 bf8_t __attribute__((ext_vector_type(8)));
typedef float f4_t __attribute__((ext_vector_type(4)));
typedef unsigned long long ull;

#define AS1 __attribute__((address_space(1)))
#define AS3 __attribute__((address_space(3)))
static __device__ __forceinline__ void gload_lds16(const void* g, void* s) {
    __builtin_amdgcn_global_load_lds((const AS1 unsigned int*)g, (AS3 unsigned int*)s, 16, 0, 0);
}

static __device__ __forceinline__ unsigned short f2bf(float x) {
    unsigned u = __float_as_uint(x);
    unsigned r = (u + 0x7fffu + ((u >> 16) & 1u)) >> 16;  // RNE
    return (unsigned short)r;
}

// min-reduction encoding: store cm = max(~bits(x)); init 0 = empty; decode
// 0 -> +inf, else x = ~cm. Valid for x >= 0.
static __device__ __forceinline__ float dec_min(unsigned cm) {
    return (cm == 0u) ? __builtin_inff() : __uint_as_float(~cm);
}

static __device__ __forceinline__ unsigned ald(const unsigned* p) {
    return __hip_atomic_load(p, __ATOMIC_RELAXED, __HIP_MEMORY_SCOPE_AGENT);
}
static __device__ __forceinline__ void ast(unsigned* p, unsigned v) {
    __hip_atomic_store(p, v, __ATOMIC_RELAXED, __HIP_MEMORY_SCOPE_AGENT);
}

// DPP row_shl reductions over a 16-lane group (VALU-rate, no DS ops).
// row_shl:N -> out[lane] = in[lane+N]; accumulates toward lane 0.
// Result valid in the LOWEST lane of each 16-group (invalid lanes keep old=v).
static __device__ __forceinline__ float rmax16(float v) {
    int s;
    s = __builtin_amdgcn_update_dpp(__float_as_int(v), __float_as_int(v), 0x101, 0xF, 0xF, false);
    v = fmaxf(v, __int_as_float(s));
    s = __builtin_amdgcn_update_dpp(__float_as_int(v), __float_as_int(v), 0x102, 0xF, 0xF, false);
    v = fmaxf(v, __int_as_float(s));
    s = __builtin_amdgcn_update_dpp(__float_as_int(v), __float_as_int(v), 0x104, 0xF, 0xF, false);
    v = fmaxf(v, __int_as_float(s));
    s = __builtin_amdgcn_update_dpp(__float_as_int(v), __float_as_int(v), 0x108, 0xF, 0xF, false);
    v = fmaxf(v, __int_as_float(s));
    return v;
}
static __device__ __forceinline__ float rmin16(float v) {
    int s;
    s = __builtin_amdgcn_update_dpp(__float_as_int(v), __float_as_int(v), 0x101, 0xF, 0xF, false);
    v = fminf(v, __int_as_float(s));
    s = __builtin_amdgcn_update_dpp(__float_as_int(v), __float_as_int(v), 0x102, 0xF, 0xF, false);
    v = fminf(v, __int_as_float(s));
    s = __builtin_amdgcn_update_dpp(__float_as_int(v), __float_as_int(v), 0x104, 0xF, 0xF, false);
    v = fminf(v, __int_as_float(s));
    s = __builtin_amdgcn_update_dpp(__float_as_int(v), __float_as_int(v), 0x108, 0xF, 0xF, false);
    v = fminf(v, __int_as_float(s));
    return v;
}

// software grid barrier (all blocks co-resident; grid <= 256 blocks)
static __device__ __forceinline__ void gridbar(unsigned* cnt, unsigned target) {
    __syncthreads();
    if (threadIdx.x == 0) {
        __threadfence();
        __hip_atomic_fetch_add(cnt, 1u, __ATOMIC_RELEASE, __HIP_MEMORY_SCOPE_AGENT);
        while (__hip_atomic_load(cnt, __ATOMIC_ACQUIRE, __HIP_MEMORY_SCOPE_AGENT) < target) {
            __builtin_amdgcn_s_sleep(8);
        }
    }
    __syncthreads();
}

// ---------------------------------------------------------------------------
// Merged top-k selection + gather. Phases separated by grid barriers.
// ALL cross-phase global data uses agent-scope atomic load/store (per-XCD L2s
// can hold stale clean lines from the memset; plain loads may read them).
__global__ __launch_bounds__(256) void k_topk(
        const float* __restrict__ conf, const float* __restrict__ emb,
        const int* __restrict__ tags, int n, int ksel, int np,
        unsigned* __restrict__ h1, unsigned* __restrict__ ctrl,
        int* __restrict__ idx_sel, ull* __restrict__ cand,
        unsigned short* __restrict__ ebf, float* __restrict__ sqn,
        int* __restrict__ lsel, unsigned* __restrict__ labhist) {
    int t = threadIdx.x;
    int gid = blockIdx.x * 256 + t;
    int stride = gridDim.x * 256;
    unsigned k = (unsigned)ksel;
    unsigned nblk = gridDim.x;

    __shared__ unsigned spart[256];
    __shared__ int schunk;
    __shared__ ull scand[2048];

    // P0: histogram of top 16 bits (conf >= 0 -> bit order = value order)
    for (int i = gid; i < n; i += stride)
        atomicAdd(&h1[__float_as_uint(conf[i]) >> 16], 1u);
    gridbar(&ctrl[16], nblk);

    // P1: suffix-scan (block 0); finds bin b16: count(>b16) < ksel <= count(>=b16)
    if (blockIdx.x == 0) {
        unsigned s = 0;
        int base = t * 256;
        #pragma unroll 8
        for (int b = 0; b < 256; b++) s += ald(&h1[base + b]);
        spart[t] = s;
        __syncthreads();
        for (int off = 1; off < 256; off <<= 1) {
            unsigned v = (t + off < 256) ? spart[t + off] : 0u;
            __syncthreads();
            spart[t] += v;
            __syncthreads();
        }
        if (spart[t] >= k && (t == 255 || spart[t + 1] < k)) schunk = t;
        __syncthreads();
        if (t == 0) {
            int c = schunk;
            unsigned cum = (c == 255) ? 0u : spart[c + 1];
            int bin = 0; unsigned rem = 1;
            for (int b = 255; b >= 0; b--) {
                unsigned h = ald(&h1[c * 256 + b]);
                if (cum + h >= k) { bin = c * 256 + b; rem = k - cum; break; }
                cum += h;
            }
            ast(&ctrl[3], (unsigned)bin);
            ast(&ctrl[1], k - rem);
            ast(&ctrl[2], rem);
        }
    }
    gridbar(&ctrl[17], nblk);

    // P2: select. gt -> slot (set order irrelevant); eq -> candidate buffer.
    unsigned b16 = ald(&ctrl[3]);
    for (int i = gid; i < n; i += stride) {
        unsigned u = __float_as_uint(conf[i]);
        unsigned t16 = u >> 16;
        if (t16 > b16) {
            unsigned pos = atomicAdd(&ctrl[5], 1u);
            __hip_atomic_store(&idx_sel[pos], i, __ATOMIC_RELAXED, __HIP_MEMORY_SCOPE_AGENT);
        } else if (t16 == b16) {
            unsigned pos = atomicAdd(&ctrl[6], 1u);
            __hip_atomic_store(&cand[pos], ((ull)u << 32) | (unsigned)i,
                               __ATOMIC_RELAXED, __HIP_MEMORY_SCOPE_AGENT);
        }
    }
    gridbar(&ctrl[18], nblk);

    // P3: boundary bin exact ranking by (value desc, index asc) — matches
    // jax.lax.top_k tie order (block 0 only)
    if (blockIdx.x == 0) {
        int M = (int)ald(&ctrl[6]);
        unsigned need = ald(&ctrl[2]), cgt = ald(&ctrl[1]);
        bool useLds = (M <= 2048);
        if (useLds) {
            for (int m = t; m < M; m += 256)
                scand[m] = __hip_atomic_load(&cand[m], __ATOMIC_RELAXED, __HIP_MEMORY_SCOPE_AGENT);
            __syncthreads();
        }
        for (int j = t; j < M; j += 256) {
            ull cj = useLds ? scand[j]
                            : __hip_atomic_load(&cand[j], __ATOMIC_RELAXED, __HIP_MEMORY_SCOPE_AGENT);
            unsigned uj = (unsigned)(cj >> 32);
            unsigned rank = 0;
            for (int m = 0; m < M; m++) {
                ull cm = useLds ? scand[m]
                                : __hip_atomic_load(&cand[m], __ATOMIC_RELAXED, __HIP_MEMORY_SCOPE_AGENT);
                unsigned um = (unsigned)(cm >> 32);
                if (um > uj || (um == uj && cm < cj)) rank++;
            }
            if (rank < need)
                __hip_atomic_store(&idx_sel[cgt + rank], (int)(unsigned)(cj & 0xFFFFFFFFu),
                                   __ATOMIC_RELAXED, __HIP_MEMORY_SCOPE_AGENT);
        }
    }
    gridbar(&ctrl[19], nblk);

    // P4: gather — one wave per row
    int gw = blockIdx.x * 4 + (t >> 6);
    int lane = t & 63;
    int nw = nblk * 4;
    for (int j = gw; j < np; j += nw) {
        if (j < ksel) {
            int src = __hip_atomic_load(&idx_sel[j], __ATOMIC_RELAXED, __HIP_MEMORY_SCOPE_AGENT);
            float4 v = *(const float4*)&emb[(size_t)src * D + lane * 4];
            ushort4 o;
            o.x = f2bf(v.x); o.y = f2bf(v.y); o.z = f2bf(v.z); o.w = f2bf(v.w);
            *(ushort4*)&ebf[(size_t)j * D + lane * 4] = o;
            float s = v.x * v.x + v.y * v.y + v.z * v.z + v.w * v.w;
            for (int off = 32; off > 0; off >>= 1) s += __shfl_down(s, off);
            if (lane == 0) {
                int lab = tags[src];
                sqn[j] = s; lsel[j] = lab;
                atomicAdd(&labhist[lab], 1u);
            }
        } else {
            ushort4 z = {0, 0, 0, 0};
            *(ushort4*)&ebf[(size_t)j * D + lane * 4] = z;
            if (lane == 0) { sqn[j] = 0.f; lsel[j] = -1; }
        }
    }
}

// ---------------------------------------------------------------------------
// Fused MFMA GEMM + mining on SQUARED distances. 128x128 triangular blocks,
// 4 waves each 64x64 (4x4 of 16x16x32 frags), BK=64.
// Staging: global_load_lds width=16 into XOR-swizzled unpadded LDS tiles.
// PASS2's last-finished block computes the final loss and writes out[0].
template <int PASS>
__global__ __launch_bounds__(256, 3) void k_fused(const unsigned short* __restrict__ Ebf,
                                                  const float* __restrict__ sqn,
                                                  const int* __restrict__ lsel,
                                                  unsigned* __restrict__ hp_g,
                                                  unsigned* __restrict__ nm_g,
                                                  unsigned* __restrict__ shn_g,
                                                  int np, int nb, int ksel,
                                                  const unsigned* __restrict__ labhist,
                                                  unsigned* __restrict__ ctrl,
                                                  float* __restrict__ out) {
    int rem = blockIdx.x, bi = 0;
    while (rem >= nb - bi) { rem -= nb - bi; bi++; }
    int bj = bi + rem;
    int i0 = bi * 128, j0 = bj * 128;
    bool diag = (bi == bj);

    __shared__ __align__(16) char smem[32768];
    char* ldsA = smem;
    char* ldsB = smem + 16384;

    int t = threadIdx.x;
    int w = t >> 6, l = t & 63;
    int wm = w & 1, wn = w >> 1;
    int lr = l & 15, lq = l >> 4;
    int r7 = lr & 7, rh = lr >> 3;

    int dr = l >> 3;
    int sg = (l & 7) ^ dr;
    const unsigned short* gA = Ebf + (size_t)(i0 + dr) * D + sg * 8;
    const unsigned short* gB = Ebf + (size_t)(j0 + dr) * D + sg * 8;

    f4_t zero = {0.f, 0.f, 0.f, 0.f};
    f4_t acc[4][4];
    #pragma unroll
    for (int p = 0; p < 4; p++)
        #pragma unroll
        for (int q = 0; q < 4; q++) acc[p][q] = zero;

    for (int k0 = 0; k0 < D; k0 += 64) {
        #pragma unroll
        for (int c = 0; c < 4; c++) {
            int R0 = w * 32 + c * 8;
            gload_lds16(gA + (size_t)R0 * D + k0, ldsA + R0 * 128);
            gload_lds16(gB + (size_t)R0 * D + k0, ldsB + R0 * 128);
        }
        __syncthreads();
        #pragma unroll
        for (int ks8 = 0; ks8 < 8; ks8 += 4) {
            bf8_t a[4], b[4];
            #pragma unroll
            for (int p = 0; p < 4; p++) {
                int off = ((wm * 8 + p * 2 + rh) << 10) + ((r7 * 8 + ((ks8 + lq) ^ r7)) << 4);
                a[p] = *(const bf8_t*)(ldsA + off);
            }
            #pragma unroll
            for (int q = 0; q < 4; q++) {
                int off = ((wn * 8 + q * 2 + rh) << 10) + ((r7 * 8 + ((ks8 + lq) ^ r7)) << 4);
                b[q] = *(const bf8_t*)(ldsB + off);
            }
            #pragma unroll
            for (int p = 0; p < 4; p++)
                #pragma unroll
                for (int q = 0; q < 4; q++)
                    acc[p][q] = __builtin_amdgcn_mfma_f32_16x16x32_bf16(a[p], b[q], acc[p][q], 0, 0, 0);
        }
        __syncthreads();
    }

    // stage sqn / labels / (pass2) hp into LDS (smem reuse after K-loop)
    float* sqnA = (float*)smem;
    float* sqnB = sqnA + 128;
    int* labA = (int*)(sqnB + 128);
    int* labB = labA + 128;
    float* hpA2 = (float*)(labB + 128);
    float* hpB2 = hpA2 + 128;
    if (t < 128) {
        sqnA[t] = sqn[i0 + t];
        labA[t] = lsel[i0 + t];
        if (PASS == 2) hpA2[t] = __uint_as_float(hp_g[i0 + t]);
    } else {
        int u = t - 128;
        sqnB[u] = sqn[j0 + u];
        labB[u] = lsel[j0 + u];
        if (PASS == 2) hpB2[u] = __uint_as_float(hp_g[j0 + u]);
    }
    __syncthreads();

    // squared distances; C/D map: col = lane&15, row = (lane>>4)*4+reg
    const float INF = __builtin_inff();
    float dsq[4][4][4];
    int colL[4], ljv[4];
    #pragma unroll
    for (int q = 0; q < 4; q++) { colL[q] = wn * 64 + q * 16 + lr; ljv[q] = labB[colL[q]]; }
    #pragma unroll
    for (int p = 0; p < 4; p++) {
        #pragma unroll
        for (int r = 0; r < 4; r++) {
            int rowL = wm * 64 + p * 16 + lq * 4 + r;
            int gm = i0 + rowL;
            float smi = sqnA[rowL];
            #pragma unroll
            for (int q = 0; q < 4; q++) {
                int gn = j0 + colL[q];
                float s = fmaxf(smi + sqnB[colL[q]] - 2.f * acc[p][q][r], 0.f);
                dsq[p][q][r] = (gm < ksel && gn < ksel) ? s : INF;
            }
        }
    }

    // row-direction reduction (DPP row_shl; result in lr==0 lanes)
    #pragma unroll
    for (int p = 0; p < 4; p++) {
        #pragma unroll
        for (int r = 0; r < 4; r++) {
            int rowL = wm * 64 + p * 16 + lq * 4 + r;
            int li = labA[rowL];
            if (PASS == 1) {
                float hpv = -INF, nmv = INF;
                #pragma unroll
                for (int q = 0; q < 4; q++) {
                    float d = dsq[p][q][r];
                    bool self = diag && (rowL == colL[q]);
                    if (ljv[q] == li) { if (!self) hpv = fmaxf(hpv, d); }
                    else nmv = fminf(nmv, d);
                }
                hpv = rmax16(hpv);
                nmv = rmin16(nmv);
                if (lr == 0) {
                    if (hpv >= 0.f) atomicMax(&hp_g[i0 + rowL], __float_as_uint(hpv));
                    if (nmv < INF) atomicMax(&nm_g[i0 + rowL], ~__float_as_uint(nmv));
                }
            } else {
                float hpr = hpA2[rowL];
                float smv = INF;
                #pragma unroll
                for (int q = 0; q < 4; q++) {
                    float d = dsq[p][q][r];
                    if (ljv[q] != li && d > hpr) smv = fminf(smv, d);
                }
                smv = rmin16(smv);
                if (lr == 0 && smv < INF) atomicMax(&shn_g[i0 + rowL], ~__float_as_uint(smv));
            }
        }
    }

    // column-direction (mirror; off-diagonal blocks only)
    if (!diag) {
        #pragma unroll
        for (int q = 0; q < 4; q++) {
            int lj = ljv[q];
            if (PASS == 1) {
                float hpv = -INF, nmv = INF;
                #pragma unroll
                for (int p = 0; p < 4; p++)
                    #pragma unroll
                    for (int r = 0; r < 4; r++) {
                        int rowL = wm * 64 + p * 16 + lq * 4 + r;
                        float d = dsq[p][q][r];
                        if (labA[rowL] == lj) hpv = fmaxf(hpv, d);
                        else nmv = fminf(nmv, d);
                    }
                hpv = fmaxf(hpv, __shfl_xor(hpv, 16));
                hpv = fmaxf(hpv, __shfl_xor(hpv, 32));
                nmv = fminf(nmv, __shfl_xor(nmv, 16));
                nmv = fminf(nmv, __shfl_xor(nmv, 32));
                if (lq == 0) {
                    if (hpv >= 0.f) atomicMax(&hp_g[j0 + colL[q]], __float_as_uint(hpv));
                    if (nmv < INF) atomicMax(&nm_g[j0 + colL[q]], ~__float_as_uint(nmv));
                }
            } else {
                float hpc = hpB2[colL[q]];
                float smv = INF;
                #pragma unroll
                for (int p = 0; p < 4; p++)
                    #pragma unroll
                    for (int r = 0; r < 4; r++) {
                        int rowL = wm * 64 + p * 16 + lq * 4 + r;
                        float d = dsq[p][q][r];
                        if (labA[rowL] != lj && d > hpc) smv = fminf(smv, d);
                    }
                smv = fminf(smv, __shfl_xor(smv, 16));
                smv = fminf(smv, __shfl_xor(smv, 32));
                if (lq == 0 && smv < INF) atomicMax(&shn_g[j0 + colL[q]], ~__float_as_uint(smv));
            }
        }
    }

    // PASS2 tail: last finished block computes the loss and writes out[0]
    if (PASS == 2) {
        __shared__ unsigned sflag;
        __syncthreads();
        if (t == 0) {
            __threadfence();
            unsigned d = __hip_atomic_fetch_add(&ctrl[20], 1u, __ATOMIC_ACQ_REL,
                                                __HIP_MEMORY_SCOPE_AGENT);
            sflag = (d == (unsigned)(gridDim.x - 1)) ? 1u : 0u;
        }
        __syncthreads();
        if (sflag) {
            float* ssum = (float*)smem;
            float* scnt = ssum + 256;
            float sum = 0.f, cnt = 0.f;
            for (int i = t; i < ksel; i += 256) {
                int li = lsel[i];
                unsigned h = labhist[li];
                bool valid = (h >= 2u) && ((unsigned)ksel > h);
                float hp2 = __uint_as_float(__hip_atomic_load(&hp_g[i], __ATOMIC_RELAXED,
                                                              __HIP_MEMORY_SCOPE_AGENT));
                float nm2 = dec_min(__hip_atomic_load(&nm_g[i], __ATOMIC_RELAXED,
                                                      __HIP_MEMORY_SCOPE_AGENT));
                float sh2 = dec_min(__hip_atomic_load(&shn_g[i], __ATOMIC_RELAXED,
                                                      __HIP_MEMORY_SCOPE_AGENT));
                float hn2 = isinf(sh2) ? nm2 : sh2;
                float lv = valid ? fmaxf(sqrtf(hp2) - sqrtf(hn2) + MARGIN, 0.f) : 0.f;
                sum += lv;
                cnt += valid ? 1.f : 0.f;
            }
            ssum[t] = sum; scnt[t] = cnt;
            __syncthreads();
            for (int off = 128; off > 0; off >>= 1) {
                if (t < off) { ssum[t] += ssum[t + off]; scnt[t] += scnt[t + off]; }
                __syncthreads();
            }
            if (t == 0) out[0] = (scnt[0] > 0.f) ? (ssum[0] / fmaxf(scnt[0], 1.f)) : 0.f;
        }
    }
}

__global__ void k_wsfail(float* out, float code) { out[0] = code; }

// ---------------------------------------------------------------------------
static inline size_t align_up(size_t x, size_t a) { return (x + a - 1) & ~(a - 1); }

extern "C" void kernel_launch(void* const* d_in, const int* in_sizes, int n_in,
                              void* d_out, int out_size, void* d_ws, size_t ws_size,
                              hipStream_t stream) {
    const float* emb  = (const float*)d_in[0];
    const int*   tags = (const int*)d_in[1];
    const float* conf = (const float*)d_in[2];
    float* out = (float*)d_out;

    int n = in_sizes[2];                        // 32768
    int ksel = (int)(0.2 * (double)n);          // 6553
    int np = ((ksel + 127) / 128) * 128;        // 6656
    int nb = np / 128;                          // 52

    // ---- zero-init region (single hipMemsetAsync covers all of it) ----
    size_t off = 0;
    size_t o_ctrl = off; off = align_up(off + 32 * sizeof(unsigned), 256);
    size_t o_lh   = off; off = align_up(off + 512 * 4, 256);
    size_t o_hp   = off; off = align_up(off + (size_t)np * 4, 256);
    size_t o_nm   = off; off = align_up(off + (size_t)np * 4, 256);
    size_t o_shn  = off; off = align_up(off + (size_t)np * 4, 256);
    size_t o_h1   = off; off = align_up(off + 65536 * 4, 256);
    size_t zero_bytes = off;
    // ---- non-zeroed ----
    size_t o_idx  = off; off = align_up(off + (size_t)ksel * 4, 256);
    size_t o_cand = off; off = align_up(off + (size_t)n * 8, 256);
    size_t o_lab  = off; off = align_up(off + (size_t)np * 4, 256);
    size_t o_sqn  = off; off = align_up(off + (size_t)np * 4, 256);
    size_t o_ebf  = off; off = align_up(off + (size_t)np * D * 2, 256);

    if (ws_size < off) {
        k_wsfail<<<1, 1, 0, stream>>>(out, -(float)(ws_size >> 20));
        return;
    }

    char* ws = (char*)d_ws;
    unsigned*       ctrl    = (unsigned*)(ws + o_ctrl);
    unsigned*       labhist = (unsigned*)(ws + o_lh);
    unsigned*       hp_g    = (unsigned*)(ws + o_hp);
    unsigned*       nm_g    = (unsigned*)(ws + o_nm);
    unsigned*       shn_g   = (unsigned*)(ws + o_shn);
    unsigned*       h1      = (unsigned*)(ws + o_h1);
    int*            idx_sel = (int*)(ws + o_idx);
    ull*            cand    = (ull*)(ws + o_cand);
    int*            lsel    = (int*)(ws + o_lab);
    float*          sqn     = (float*)(ws + o_sqn);
    unsigned short* ebf     = (unsigned short*)(ws + o_ebf);

    hipMemsetAsync(d_ws, 0, zero_bytes, stream);
    k_topk<<<256, 256, 0, stream>>>(conf, emb, tags, n, ksel, np,
                                    h1, ctrl, idx_sel, cand, ebf, sqn, lsel, labhist);
    int ntri = nb * (nb + 1) / 2;
    k_fused<1><<<ntri, 256, 0, stream>>>(ebf, sqn, lsel, hp_g, nm_g, shn_g, np, nb, ksel,
                                         labhist, ctrl, out);
    k_fused<2><<<ntri, 256, 0, stream>>>(ebf, sqn, lsel, hp_g, nm_g, shn_g, np, nb, ksel,
                                         labhist, ctrl, out);
}

// Round 10
// 185.892 us; speedup vs baseline: 5.0749x; 5.0749x over previous
//
#include <hip/hip_runtime.h>
#include <math.h>

#define D 256
#define MARGIN 0.075f
#define MAXM 96   // max members per label tracked (P(overflow) ~ 0 for lambda≈13)

typedef __bf16 bf8_t __attribute__((ext_vector_type(8)));
typedef float f4_t __attribute__((ext_vector_type(4)));
typedef unsigned long long ull;

#define AS1 __attribute__((address_space(1)))
#define AS3 __attribute__((address_space(3)))
static __device__ __forceinline__ void gload_lds16(const void* g, void* s) {
    __builtin_amdgcn_global_load_lds((const AS1 unsigned int*)g, (AS3 unsigned int*)s, 16, 0, 0);
}

static __device__ __forceinline__ unsigned short f2bf(float x) {
    unsigned u = __float_as_uint(x);
    unsigned r = (u + 0x7fffu + ((u >> 16) & 1u)) >> 16;  // RNE
    return (unsigned short)r;
}

// min-reduction encoding: store cm = max(~bits(x)); init 0 = empty; decode
// 0 -> +inf, else x = ~cm. Valid for x >= 0.
static __device__ __forceinline__ float dec_min(unsigned cm) {
    return (cm == 0u) ? __builtin_inff() : __uint_as_float(~cm);
}

// DPP row_shl reductions over a 16-lane group; result in the LOWEST lane.
// row_shl:N -> out[lane] = in[lane+N]; bound_ctrl=false keeps old on invalid.
static __device__ __forceinline__ float rmin16(float v) {
    int s;
    s = __builtin_amdgcn_update_dpp(__float_as_int(v), __float_as_int(v), 0x101, 0xF, 0xF, false);
    v = fminf(v, __int_as_float(s));
    s = __builtin_amdgcn_update_dpp(__float_as_int(v), __float_as_int(v), 0x102, 0xF, 0xF, false);
    v = fminf(v, __int_as_float(s));
    s = __builtin_amdgcn_update_dpp(__float_as_int(v), __float_as_int(v), 0x104, 0xF, 0xF, false);
    v = fminf(v, __int_as_float(s));
    s = __builtin_amdgcn_update_dpp(__float_as_int(v), __float_as_int(v), 0x108, 0xF, 0xF, false);
    v = fminf(v, __int_as_float(s));
    return v;
}

// ---------------------------------------------------------------------------
// 16-bit histogram of the float keys (conf >= 0 -> bit order = value order)
__global__ void k_hist1(const float* __restrict__ conf, int n,
                        unsigned* __restrict__ hist) {
    int i = blockIdx.x * blockDim.x + threadIdx.x;
    if (i < n) atomicAdd(&hist[__float_as_uint(conf[i]) >> 16], 1u);
}

// suffix-scan the 65536-bin histogram: bin b16 with
// count(>b16) < ksel <= count(>=b16).  ctrl[3]=b16 ctrl[1]=count_gt ctrl[2]=need
__global__ __launch_bounds__(1024) void k_scan(const unsigned* __restrict__ hist,
                                               unsigned* __restrict__ ctrl, int ksel) {
    __shared__ unsigned part[1024];
    __shared__ int schunk;
    int t = threadIdx.x;
    unsigned k = (unsigned)ksel;
    unsigned s = 0;
    const uint4* h4 = (const uint4*)(hist + t * 64);
    #pragma unroll
    for (int b = 0; b < 16; b++) { uint4 v = h4[b]; s += v.x + v.y + v.z + v.w; }
    part[t] = s;
    __syncthreads();
    for (int off = 1; off < 1024; off <<= 1) {
        unsigned v = (t + off < 1024) ? part[t + off] : 0u;
        __syncthreads();
        part[t] += v;
        __syncthreads();
    }
    if (part[t] >= k && (t == 1023 || part[t + 1] < k)) schunk = t;
    __syncthreads();
    if (t == 0) {
        int c = schunk;
        unsigned cum = (c == 1023) ? 0u : part[c + 1];
        int bin = 0; unsigned rem = 1;
        for (int b = 63; b >= 0; b--) {
            unsigned h = hist[c * 64 + b];
            if (cum + h >= k) { bin = c * 64 + b; rem = k - cum; break; }
            cum += h;
        }
        ctrl[3] = (unsigned)bin;
        ctrl[1] = k - rem;
        ctrl[2] = rem;
    }
}

// selection: t16 > b16 -> slot (set order irrelevant to the loss);
// t16 == b16 -> candidate buffer for exact boundary resolution
__global__ void k_sel(const float* __restrict__ conf, int n,
                      unsigned* __restrict__ ctrl, int* __restrict__ idx_sel,
                      ull* __restrict__ cand) {
    int i = blockIdx.x * blockDim.x + threadIdx.x;
    if (i < n) {
        unsigned u = __float_as_uint(conf[i]);
        unsigned t16 = u >> 16, b16 = ctrl[3];
        if (t16 > b16) {
            unsigned pos = atomicAdd(&ctrl[5], 1u);
            idx_sel[pos] = i;
        } else if (t16 == b16) {
            unsigned pos = atomicAdd(&ctrl[6], 1u);
            cand[pos] = ((ull)u << 32) | (unsigned)i;
        }
    }
}

// boundary bin: rank by (value desc, index asc) — exact jax.lax.top_k order
__global__ __launch_bounds__(256) void k_sel2(const unsigned* __restrict__ ctrl,
                                              const ull* __restrict__ cand,
                                              int* __restrict__ idx_sel) {
    int t = threadIdx.x;
    int M = (int)ctrl[6];
    unsigned need = ctrl[2], cgt = ctrl[1];
    for (int j = t; j < M; j += 256) {
        ull cj = cand[j];
        unsigned uj = (unsigned)(cj >> 32);
        unsigned rank = 0;
        for (int m = 0; m < M; m++) {
            ull cm = cand[m];
            unsigned um = (unsigned)(cm >> 32);
            if (um > uj || (um == uj && cm < cj)) rank++;
        }
        if (rank < need) idx_sel[cgt + rank] = (int)(unsigned)(cj & 0xFFFFFFFFu);
    }
}

// ---------------------------------------------------------------------------
// gather rows -> bf16, fp32 sq-norms, labels, label histogram + member lists
__global__ void k_gather(const float* __restrict__ emb, const int* __restrict__ tags,
                         const int* __restrict__ idx_sel, int ksel, int np,
                         unsigned short* __restrict__ ebf, float* __restrict__ sqn,
                         int* __restrict__ lsel, unsigned* __restrict__ labhist,
                         int* __restrict__ members) {
    int j = blockIdx.x;   // < np
    int t = threadIdx.x;  // 64
    if (j < ksel) {
        int src = idx_sel[j];
        float4 v = *(const float4*)&emb[(size_t)src * D + t * 4];
        ushort4 o;
        o.x = f2bf(v.x); o.y = f2bf(v.y); o.z = f2bf(v.z); o.w = f2bf(v.w);
        *(ushort4*)&ebf[(size_t)j * D + t * 4] = o;
        float s = v.x * v.x + v.y * v.y + v.z * v.z + v.w * v.w;
        for (int off = 32; off > 0; off >>= 1) s += __shfl_down(s, off);
        if (t == 0) {
            int lab = tags[src];
            sqn[j] = s; lsel[j] = lab;
            unsigned slot = atomicAdd(&labhist[lab], 1u);
            if (slot < MAXM) members[lab * MAXM + slot] = j;
        }
    } else {
        ushort4 z = {0, 0, 0, 0};
        *(ushort4*)&ebf[(size_t)j * D + t * 4] = z;
        if (t == 0) { sqn[j] = 0.f; lsel[j] = -1; }
    }
}

// ---------------------------------------------------------------------------
// hard_pos^2 per anchor from same-label pairs only (~13 members/label).
// One block per label; pairwise bf16 dot products with fp32 accumulate.
__global__ __launch_bounds__(256) void k_hardpos(const unsigned short* __restrict__ ebf,
                                                 const float* __restrict__ sqn,
                                                 const int* __restrict__ members,
                                                 const unsigned* __restrict__ labhist,
                                                 unsigned* __restrict__ hp_g) {
    int L = blockIdx.x;
    int t = threadIdx.x;
    int m = (int)labhist[L];
    if (m > MAXM) m = MAXM;
    if (m < 2) return;   // no positive pairs; hp_g stays 0 (anchor invalid anyway)

    __shared__ unsigned short rows[MAXM * 256];
    __shared__ float lsqn[MAXM];
    __shared__ unsigned hpl[MAXM];
    __shared__ int ridx[MAXM];

    for (int a = t; a < m; a += 256) {
        int r = members[L * MAXM + a];
        ridx[a] = r; lsqn[a] = sqn[r]; hpl[a] = 0u;
    }
    __syncthreads();
    for (int e = t * 8; e < m * 256; e += 256 * 8) {
        int a = e >> 8, c = e & 255;
        *(uint4*)&rows[a * 256 + c] = *(const uint4*)&ebf[(size_t)ridx[a] * D + c];
    }
    __syncthreads();

    int npair = m * (m - 1) / 2;
    for (int pidx = t; pidx < npair; pidx += 256) {
        int a = 0, rem = pidx;
        while (rem >= m - 1 - a) { rem -= m - 1 - a; a++; }
        int b = a + 1 + rem;
        const unsigned* ra = (const unsigned*)&rows[a * 256];
        const unsigned* rb = (const unsigned*)&rows[b * 256];
        float dot = 0.f;
        #pragma unroll 8
        for (int c = 0; c < 128; c++) {
            unsigned ua = ra[c], ub = rb[c];
            float a0 = __uint_as_float(ua << 16);
            float a1 = __uint_as_float(ua & 0xFFFF0000u);
            float b0 = __uint_as_float(ub << 16);
            float b1 = __uint_as_float(ub & 0xFFFF0000u);
            dot = fmaf(a0, b0, dot);
            dot = fmaf(a1, b1, dot);
        }
        float dsq = fmaxf(lsqn[a] + lsqn[b] - 2.f * dot, 0.f);
        unsigned bits = __float_as_uint(dsq);
        atomicMax(&hpl[a], bits);
        atomicMax(&hpl[b], bits);
    }
    __syncthreads();
    for (int a = t; a < m; a += 256) hp_g[ridx[a]] = hpl[a];
}

// ---------------------------------------------------------------------------
// SINGLE-PASS fused MFMA GEMM + mining on SQUARED distances. hard_pos is
// precomputed, so neg_min and semi-hard min are mined together.
// 128x128 triangular blocks, 4 waves each 64x64 (4x4 of 16x16x32), BK=64.
// Staging: global_load_lds width=16 into XOR-swizzled unpadded LDS tiles.
__global__ __launch_bounds__(256, 3) void k_fused(const unsigned short* __restrict__ Ebf,
                                                  const float* __restrict__ sqn,
                                                  const int* __restrict__ lsel,
                                                  const unsigned* __restrict__ hp_g,
                                                  unsigned* __restrict__ nm_g,
                                                  unsigned* __restrict__ shn_g,
                                                  int np, int nb, int ksel) {
    int rem = blockIdx.x, bi = 0;
    while (rem >= nb - bi) { rem -= nb - bi; bi++; }
    int bj = bi + rem;
    int i0 = bi * 128, j0 = bj * 128;
    bool diag = (bi == bj);

    __shared__ __align__(16) char smem[32768];
    char* ldsA = smem;
    char* ldsB = smem + 16384;

    int t = threadIdx.x;
    int w = t >> 6, l = t & 63;
    int wm = w & 1, wn = w >> 1;
    int lr = l & 15, lq = l >> 4;
    int r7 = lr & 7, rh = lr >> 3;

    int dr = l >> 3;
    int sg = (l & 7) ^ dr;
    const unsigned short* gA = Ebf + (size_t)(i0 + dr) * D + sg * 8;
    const unsigned short* gB = Ebf + (size_t)(j0 + dr) * D + sg * 8;

    f4_t zero = {0.f, 0.f, 0.f, 0.f};
    f4_t acc[4][4];
    #pragma unroll
    for (int p = 0; p < 4; p++)
        #pragma unroll
        for (int q = 0; q < 4; q++) acc[p][q] = zero;

    for (int k0 = 0; k0 < D; k0 += 64) {
        #pragma unroll
        for (int c = 0; c < 4; c++) {
            int R0 = w * 32 + c * 8;
            gload_lds16(gA + (size_t)R0 * D + k0, ldsA + R0 * 128);
            gload_lds16(gB + (size_t)R0 * D + k0, ldsB + R0 * 128);
        }
        __syncthreads();
        #pragma unroll
        for (int ks8 = 0; ks8 < 8; ks8 += 4) {
            bf8_t a[4], b[4];
            #pragma unroll
            for (int p = 0; p < 4; p++) {
                int off = ((wm * 8 + p * 2 + rh) << 10) + ((r7 * 8 + ((ks8 + lq) ^ r7)) << 4);
                a[p] = *(const bf8_t*)(ldsA + off);
            }
            #pragma unroll
            for (int q = 0; q < 4; q++) {
                int off = ((wn * 8 + q * 2 + rh) << 10) + ((r7 * 8 + ((ks8 + lq) ^ r7)) << 4);
                b[q] = *(const bf8_t*)(ldsB + off);
            }
            #pragma unroll
            for (int p = 0; p < 4; p++)
                #pragma unroll
                for (int q = 0; q < 4; q++)
                    acc[p][q] = __builtin_amdgcn_mfma_f32_16x16x32_bf16(a[p], b[q], acc[p][q], 0, 0, 0);
        }
        __syncthreads();
    }

    // stage sqn / labels / hard_pos^2 into LDS (smem reuse after K-loop)
    float* sqnA = (float*)smem;
    float* sqnB = sqnA + 128;
    int* labA = (int*)(sqnB + 128);
    int* labB = labA + 128;
    float* hpA2 = (float*)(labB + 128);
    float* hpB2 = hpA2 + 128;
    if (t < 128) {
        sqnA[t] = sqn[i0 + t];
        labA[t] = lsel[i0 + t];
        hpA2[t] = __uint_as_float(hp_g[i0 + t]);
    } else {
        int u = t - 128;
        sqnB[u] = sqn[j0 + u];
        labB[u] = lsel[j0 + u];
        hpB2[u] = __uint_as_float(hp_g[j0 + u]);
    }
    __syncthreads();

    // squared distances; C/D map: col = lane&15, row = (lane>>4)*4+reg
    const float INF = __builtin_inff();
    float dsq[4][4][4];
    int colL[4], ljv[4];
    #pragma unroll
    for (int q = 0; q < 4; q++) { colL[q] = wn * 64 + q * 16 + lr; ljv[q] = labB[colL[q]]; }
    #pragma unroll
    for (int p = 0; p < 4; p++) {
        #pragma unroll
        for (int r = 0; r < 4; r++) {
            int rowL = wm * 64 + p * 16 + lq * 4 + r;
            int gm = i0 + rowL;
            float smi = sqnA[rowL];
            #pragma unroll
            for (int q = 0; q < 4; q++) {
                int gn = j0 + colL[q];
                float s = fmaxf(smi + sqnB[colL[q]] - 2.f * acc[p][q][r], 0.f);
                dsq[p][q][r] = (gm < ksel && gn < ksel) ? s : INF;
            }
        }
    }

    // row-direction: neg_min + semi-hard min (DPP row_shl; result in lr==0)
    #pragma unroll
    for (int p = 0; p < 4; p++) {
        #pragma unroll
        for (int r = 0; r < 4; r++) {
            int rowL = wm * 64 + p * 16 + lq * 4 + r;
            int li = labA[rowL];
            float hpr = hpA2[rowL];
            float nmv = INF, smv = INF;
            #pragma unroll
            for (int q = 0; q < 4; q++) {
                float d = dsq[p][q][r];
                if (ljv[q] != li) {
                    nmv = fminf(nmv, d);
                    if (d > hpr) smv = fminf(smv, d);
                }
            }
            nmv = rmin16(nmv);
            smv = rmin16(smv);
            if (lr == 0) {
                if (nmv < INF) atomicMax(&nm_g[i0 + rowL], ~__float_as_uint(nmv));
                if (smv < INF) atomicMax(&shn_g[i0 + rowL], ~__float_as_uint(smv));
            }
        }
    }

    // column-direction (mirror; off-diagonal blocks only)
    if (!diag) {
        #pragma unroll
        for (int q = 0; q < 4; q++) {
            int lj = ljv[q];
            float hpc = hpB2[colL[q]];
            float nmv = INF, smv = INF;
            #pragma unroll
            for (int p = 0; p < 4; p++)
                #pragma unroll
                for (int r = 0; r < 4; r++) {
                    int rowL = wm * 64 + p * 16 + lq * 4 + r;
                    float d = dsq[p][q][r];
                    if (labA[rowL] != lj) {
                        nmv = fminf(nmv, d);
                        if (d > hpc) smv = fminf(smv, d);
                    }
                }
            nmv = fminf(nmv, __shfl_xor(nmv, 16));
            nmv = fminf(nmv, __shfl_xor(nmv, 32));
            smv = fminf(smv, __shfl_xor(smv, 16));
            smv = fminf(smv, __shfl_xor(smv, 32));
            if (lq == 0) {
                if (nmv < INF) atomicMax(&nm_g[j0 + colL[q]], ~__float_as_uint(nmv));
                if (smv < INF) atomicMax(&shn_g[j0 + colL[q]], ~__float_as_uint(smv));
            }
        }
    }
}

// ---------------------------------------------------------------------------
// loss reduction + final output (last finished block writes out)
__global__ __launch_bounds__(256) void k_loss(const unsigned* __restrict__ hp,
                                              const unsigned* __restrict__ nm,
                                              const unsigned* __restrict__ shn,
                                              const int* __restrict__ lsel,
                                              const unsigned* __restrict__ labhist,
                                              int ksel, float* __restrict__ fsums,
                                              unsigned* __restrict__ ctrl,
                                              float* __restrict__ out) {
    __shared__ float ssum[256], scnt[256];
    int t = threadIdx.x;
    int i = blockIdx.x * 256 + t;
    float sum = 0.f, cnt = 0.f;
    if (i < ksel) {
        int li = lsel[i];
        unsigned h = labhist[li];
        bool valid = (h >= 2u) && ((unsigned)ksel > h);
        float hp2 = __uint_as_float(hp[i]);
        float nm2 = dec_min(nm[i]);
        float sh2 = dec_min(shn[i]);
        float hn2 = isinf(sh2) ? nm2 : sh2;
        float lv = valid ? fmaxf(sqrtf(hp2) - sqrtf(hn2) + MARGIN, 0.f) : 0.f;
        sum = lv;
        cnt = valid ? 1.f : 0.f;
    }
    ssum[t] = sum; scnt[t] = cnt;
    __syncthreads();
    for (int off = 128; off > 0; off >>= 1) {
        if (t < off) { ssum[t] += ssum[t + off]; scnt[t] += scnt[t + off]; }
        __syncthreads();
    }
    if (t == 0) {
        atomicAdd(&fsums[0], ssum[0]);
        atomicAdd(&fsums[1], scnt[0]);
        __threadfence();
        unsigned done = atomicAdd(&ctrl[7], 1u);
        if (done == gridDim.x - 1) {
            float s = atomicAdd(&fsums[0], 0.f);
            float c = atomicAdd(&fsums[1], 0.f);
            out[0] = (c > 0.f) ? (s / fmaxf(c, 1.f)) : 0.f;
        }
    }
}

__global__ void k_wsfail(float* out, float code) { out[0] = code; }

// ---------------------------------------------------------------------------
static inline size_t align_up(size_t x, size_t a) { return (x + a - 1) & ~(a - 1); }

extern "C" void kernel_launch(void* const* d_in, const int* in_sizes, int n_in,
                              void* d_out, int out_size, void* d_ws, size_t ws_size,
                              hipStream_t stream) {
    const float* emb  = (const float*)d_in[0];
    const int*   tags = (const int*)d_in[1];
    const float* conf = (const float*)d_in[2];
    float* out = (float*)d_out;

    int n = in_sizes[2];                        // 32768
    int ksel = (int)(0.2 * (double)n);          // 6553
    int np = ((ksel + 127) / 128) * 128;        // 6656
    int nb = np / 128;                          // 52
    int nlab = 512;                             // tags in [0,500)

    // ---- zero-init region (single hipMemsetAsync covers all of it) ----
    size_t off = 0;
    size_t o_ctrl = off; off = align_up(off + 32 * sizeof(unsigned), 256);
    size_t o_fs   = off; off = align_up(off + 8 * sizeof(float), 256);
    size_t o_lh   = off; off = align_up(off + (size_t)nlab * 4, 256);
    size_t o_hp   = off; off = align_up(off + (size_t)np * 4, 256);
    size_t o_nm   = off; off = align_up(off + (size_t)np * 4, 256);
    size_t o_shn  = off; off = align_up(off + (size_t)np * 4, 256);
    size_t o_h1   = off; off = align_up(off + 65536 * 4, 256);
    size_t zero_bytes = off;
    // ---- non-zeroed ----
    size_t o_idx  = off; off = align_up(off + (size_t)ksel * 4, 256);
    size_t o_cand = off; off = align_up(off + (size_t)n * 8, 256);
    size_t o_mem  = off; off = align_up(off + (size_t)nlab * MAXM * 4, 256);
    size_t o_lab  = off; off = align_up(off + (size_t)np * 4, 256);
    size_t o_sqn  = off; off = align_up(off + (size_t)np * 4, 256);
    size_t o_ebf  = off; off = align_up(off + (size_t)np * D * 2, 256);

    if (ws_size < off) {
        k_wsfail<<<1, 1, 0, stream>>>(out, -(float)(ws_size >> 20));
        return;
    }

    char* ws = (char*)d_ws;
    unsigned*       ctrl    = (unsigned*)(ws + o_ctrl);
    float*          fsums   = (float*)(ws + o_fs);
    unsigned*       labhist = (unsigned*)(ws + o_lh);
    unsigned*       hp_g    = (unsigned*)(ws + o_hp);
    unsigned*       nm_g    = (unsigned*)(ws + o_nm);
    unsigned*       shn_g   = (unsigned*)(ws + o_shn);
    unsigned*       h1      = (unsigned*)(ws + o_h1);
    int*            idx_sel = (int*)(ws + o_idx);
    ull*            cand    = (ull*)(ws + o_cand);
    int*            members = (int*)(ws + o_mem);
    int*            lsel    = (int*)(ws + o_lab);
    float*          sqn     = (float*)(ws + o_sqn);
    unsigned short* ebf     = (unsigned short*)(ws + o_ebf);

    hipMemsetAsync(d_ws, 0, zero_bytes, stream);
    k_hist1<<<(n + 255) / 256, 256, 0, stream>>>(conf, n, h1);
    k_scan<<<1, 1024, 0, stream>>>(h1, ctrl, ksel);
    k_sel<<<(n + 255) / 256, 256, 0, stream>>>(conf, n, ctrl, idx_sel, cand);
    k_sel2<<<1, 256, 0, stream>>>(ctrl, cand, idx_sel);
    k_gather<<<np, 64, 0, stream>>>(emb, tags, idx_sel, ksel, np, ebf, sqn, lsel,
                                    labhist, members);
    k_hardpos<<<512, 256, 0, stream>>>(ebf, sqn, members, labhist, hp_g);
    int ntri = nb * (nb + 1) / 2;
    k_fused<<<ntri, 256, 0, stream>>>(ebf, sqn, lsel, hp_g, nm_g, shn_g, np, nb, ksel);
    k_loss<<<(ksel + 255) / 256, 256, 0, stream>>>(hp_g, nm_g, shn_g, lsel, labhist,
                                                   ksel, fsums, ctrl, out);
}